// Round 11
// baseline (269.656 us; speedup 1.0000x reference)
//
#include <hip/hip_runtime.h>

// GraphSAGE 3-layer (mean agg), N=100000, E=1600000, 128->32->32->16.
// Round 11: proj occupancy fix. Round 10's proj was wave-starved (3 blocks/CU
// x 4 waves = 12 waves/CU; VALUBusy 29% matched the arithmetic exactly).
// Now NPT=2 (NT=64, grid=1563 => ~6 blocks/CU) and NO LDS in proj: W read
// directly from global (32KB, L1/L2-resident, uniform across waves), no
// staging barrier. launch_bounds(256,6) caps VGPR for 6 waves/SIMD.

#define BLOCK 256
#define NBLK 256            // blocks for hist/part passes
#define BSH 9               // 512 nodes per bucket
#define CAP 12288           // max edges per bucket staged in LDS

// ---------------- phase 1: per-(bucket,block) histogram of dst ----------------
__global__ void hist_kernel(const int* __restrict__ dst, int* __restrict__ hist,
                            int n_edges, int nbuk, int ch) {
    __shared__ int cnt[256];
    int tid = threadIdx.x;
    for (int i = tid; i < nbuk; i += BLOCK) cnt[i] = 0;
    __syncthreads();
    int e0 = blockIdx.x * ch;
    int e1 = e0 + ch; if (e1 > n_edges) e1 = n_edges;
    for (int e = e0 + tid; e < e1; e += BLOCK)
        atomicAdd(&cnt[dst[e] >> BSH], 1);
    __syncthreads();
    for (int i = tid; i < nbuk; i += BLOCK)
        hist[i * NBLK + blockIdx.x] = cnt[i];
}

// ---------------- phase 2a: per-bucket exclusive scan of its 256 block-counts ----------------
__global__ void scanBlk_kernel(int* __restrict__ hist, int* __restrict__ buktot) {
    int b = blockIdx.x;
    int tid = threadIdx.x;
    int orig = hist[b * NBLK + tid];
    int v = orig;
    int lane = tid & 63, w = tid >> 6;
#pragma unroll
    for (int off = 1; off < 64; off <<= 1) {
        int u = __shfl_up(v, off);
        if (lane >= off) v += u;
    }
    __shared__ int wps[4];
    if (lane == 63) wps[w] = v;
    __syncthreads();
    int wadd = 0;
    for (int k = 0; k < w; ++k) wadd += wps[k];
    int excl = v - orig + wadd;
    hist[b * NBLK + tid] = excl;
    if (tid == 255) buktot[b] = excl + orig;
}

// ---------------- phase 2b: exclusive scan of bucket totals (1 block) ----------------
__global__ void scanBuk_kernel(const int* __restrict__ buktot, int* __restrict__ bukoff,
                               int nbuk, int* __restrict__ startp, int n_nodes, int n_edges) {
    int tid = threadIdx.x;
    int orig = (tid < nbuk) ? buktot[tid] : 0;
    int v = orig;
    int lane = tid & 63, w = tid >> 6;
#pragma unroll
    for (int off = 1; off < 64; off <<= 1) {
        int u = __shfl_up(v, off);
        if (lane >= off) v += u;
    }
    __shared__ int wps[4];
    if (lane == 63) wps[w] = v;
    __syncthreads();
    int wadd = 0;
    for (int k = 0; k < w; ++k) wadd += wps[k];
    int excl = v - orig + wadd;
    if (tid < nbuk) bukoff[tid] = excl;
    if (tid == 0) { bukoff[nbuk] = n_edges; startp[n_nodes] = n_edges; }
}

// ---------------- phase 3: partition (src,dst) pairs bucket-contiguously ----------------
__global__ void part_kernel(const int* __restrict__ src, const int* __restrict__ dst,
                            const int* __restrict__ hist, const int* __restrict__ bukoff,
                            int2* __restrict__ pairs, int n_edges, int nbuk, int ch) {
    __shared__ int base[256];
    __shared__ int cnt[256];
    int tid = threadIdx.x;
    for (int i = tid; i < nbuk; i += BLOCK) {
        base[i] = hist[i * NBLK + blockIdx.x] + bukoff[i];
        cnt[i] = 0;
    }
    __syncthreads();
    int e0 = blockIdx.x * ch;
    int e1 = e0 + ch; if (e1 > n_edges) e1 = n_edges;
    for (int e = e0 + tid; e < e1; e += BLOCK) {
        int d = dst[e];
        int b = d >> BSH;
        int r = atomicAdd(&cnt[b], 1);
        pairs[base[b] + r] = make_int2(src[e], d);
    }
}

// ---------------- phase 4: per-bucket CSR build in LDS ----------------
__global__ void build_kernel(const int2* __restrict__ pairs, const int* __restrict__ bukoff,
                             int* __restrict__ start, float* __restrict__ invdeg,
                             int* __restrict__ csr_src, int n_nodes) {
    __shared__ int deg[512];
    __shared__ int lst[512];
    __shared__ int cur[512];
    __shared__ int wps[4];
    __shared__ int scsr[CAP];

    int b = blockIdx.x;
    int tid = threadIdx.x;
    int e0 = bukoff[b];
    int e1 = bukoff[b + 1];
    int lo = b << BSH;
    int hi = lo + (1 << BSH); if (hi > n_nodes) hi = n_nodes;
    int nn = hi - lo;
    int ne = e1 - e0;

    for (int i = tid; i < 512; i += BLOCK) deg[i] = 0;
    __syncthreads();
    for (int i = e0 + tid; i < e1; i += BLOCK)
        atomicAdd(&deg[pairs[i].y - lo], 1);
    __syncthreads();

    int d0 = deg[2 * tid], d1 = deg[2 * tid + 1];
    int s = d0 + d1;
    int lane = tid & 63, w = tid >> 6;
    int v = s;
#pragma unroll
    for (int off = 1; off < 64; off <<= 1) {
        int u = __shfl_up(v, off);
        if (lane >= off) v += u;
    }
    if (lane == 63) wps[w] = v;
    __syncthreads();
    int wb = 0;
    for (int k = 0; k < w; ++k) wb += wps[k];
    int excl = wb + v - s;
    lst[2 * tid] = excl;
    lst[2 * tid + 1] = excl + d0;
    cur[2 * tid] = 0;
    cur[2 * tid + 1] = 0;
    __syncthreads();

    for (int i = tid; i < nn; i += BLOCK) {
        start[lo + i] = e0 + lst[i];
        int d = deg[i];
        invdeg[lo + i] = 1.0f / (float)(d < 1 ? 1 : d);
    }

    if (ne <= CAP) {
        for (int i = e0 + tid; i < e1; i += BLOCK) {
            int2 pr = pairs[i];
            int dl = pr.y - lo;
            int sl = lst[dl] + atomicAdd(&cur[dl], 1);
            scsr[sl] = pr.x;
        }
        __syncthreads();
        for (int i = tid; i < ne; i += BLOCK) csr_src[e0 + i] = scsr[i];
    } else {
        for (int i = e0 + tid; i < e1; i += BLOCK) {
            int2 pr = pairs[i];
            int dl = pr.y - lo;
            int sl = lst[dl] + atomicAdd(&cur[dl], 1);
            csr_src[e0 + sl] = pr.x;
        }
    }
}

// ---------------- projection: pre = h@Ws + b ; p = h@Wn ----------------
// No LDS. W/bias read directly from global (L1/L2-resident, uniform within an
// 8-lane output-group). x read as float4 broadcast. NPT=2 -> NT=64 -> grid
// ~1563 blocks (~6/CU) for occupancy.
template<int DIN, int DOUT, int OPT, int NPT>
__global__ __launch_bounds__(256, 6)
void proj_reg(const float* __restrict__ h,
              const float* __restrict__ Ws,
              const float* __restrict__ Wn,
              const float* __restrict__ bias,
              float* __restrict__ pre,
              float* __restrict__ p,
              int n_nodes) {
    constexpr int OD  = 2 * DOUT;
    constexpr int OG  = OD / OPT;       // output groups
    constexpr int NG  = 256 / OG;       // node groups
    constexpr int NT  = NPT * NG;       // node tile
    constexpr int NV  = OPT / 4;        // float4s of output per thread

    const int tid = threadIdx.x;
    const int to = tid % OG;
    const int tn = tid / OG;
    const int o0 = to * OPT;
    const int node0 = blockIdx.x * NT + tn * NPT;

    const bool self_half = (o0 < DOUT);
    const int oo = self_half ? o0 : (o0 - DOUT);
    const float* __restrict__ W = self_half ? Ws : Wn;   // [DIN][DOUT], cols oo..oo+OPT-1

    const float4* __restrict__ xp[NPT];
#pragma unroll
    for (int n = 0; n < NPT; ++n) {
        int node = node0 + n;
        int safe = (node < n_nodes) ? node : (n_nodes - 1);
        xp[n] = reinterpret_cast<const float4*>(h + (size_t)safe * DIN);
    }

    float acc[NPT][OPT];
#pragma unroll
    for (int n = 0; n < NPT; ++n)
#pragma unroll
        for (int o = 0; o < OPT; ++o) acc[n][o] = 0.f;

#pragma unroll 2
    for (int k4 = 0; k4 < DIN / 4; ++k4) {
        float4 xv[NPT];
#pragma unroll
        for (int n = 0; n < NPT; ++n) xv[n] = xp[n][k4];
#pragma unroll
        for (int kk = 0; kk < 4; ++kk) {
            int k = 4 * k4 + kk;
            float4 w[NV];
#pragma unroll
            for (int v = 0; v < NV; ++v)
                w[v] = *reinterpret_cast<const float4*>(W + (size_t)k * DOUT + oo + 4 * v);
#pragma unroll
            for (int n = 0; n < NPT; ++n) {
                float xk = reinterpret_cast<const float*>(&xv[n])[kk];
#pragma unroll
                for (int v = 0; v < NV; ++v) {
                    acc[n][4 * v + 0] = fmaf(xk, w[v].x, acc[n][4 * v + 0]);
                    acc[n][4 * v + 1] = fmaf(xk, w[v].y, acc[n][4 * v + 1]);
                    acc[n][4 * v + 2] = fmaf(xk, w[v].z, acc[n][4 * v + 2]);
                    acc[n][4 * v + 3] = fmaf(xk, w[v].w, acc[n][4 * v + 3]);
                }
            }
        }
    }

    float* __restrict__ dstbuf = self_half ? pre : p;
#pragma unroll
    for (int n = 0; n < NPT; ++n) {
        int node = node0 + n;
        if (node >= n_nodes) continue;
#pragma unroll
        for (int v = 0; v < NV; ++v) {
            float4 r;
            r.x = acc[n][4 * v + 0];
            r.y = acc[n][4 * v + 1];
            r.z = acc[n][4 * v + 2];
            r.w = acc[n][4 * v + 3];
            if (self_half) {
                r.x += bias[oo + 4 * v + 0];
                r.y += bias[oo + 4 * v + 1];
                r.z += bias[oo + 4 * v + 2];
                r.w += bias[oo + 4 * v + 3];
            }
            *reinterpret_cast<float4*>(dstbuf + (size_t)node * DOUT + oo + 4 * v) = r;
        }
    }
}

// ---------------- float4 sub-group gather + finalize ----------------
template<int D, bool RELU>
__global__ void gather_kernel(const float* __restrict__ p,
                              const int* __restrict__ csr_src,
                              const int* __restrict__ start,
                              const float* __restrict__ pre,
                              const float* __restrict__ invdeg,
                              float* __restrict__ out,
                              int n_nodes) {
    constexpr int LPN = D / 4;
    constexpr int NPG = 64 / LPN;
    int wave = threadIdx.x >> 6;
    int lane = threadIdx.x & 63;
    int g = blockIdx.x * (blockDim.x >> 6) + wave;
    if (g >= n_nodes) return;
    int sub = lane / LPN;
    int fl  = lane % LPN;
    int s0 = start[g];
    int s1 = start[g + 1];
    const float4* __restrict__ p4 = reinterpret_cast<const float4*>(p);
    float4 a0 = make_float4(0.f, 0.f, 0.f, 0.f);
    float4 a1 = make_float4(0.f, 0.f, 0.f, 0.f);
    int j = s0 + sub;
    for (; j + NPG < s1; j += 2 * NPG) {
        int c0 = csr_src[j];
        int c1 = csr_src[j + NPG];
        float4 v0 = p4[c0 * LPN + fl];
        float4 v1 = p4[c1 * LPN + fl];
        a0.x += v0.x; a0.y += v0.y; a0.z += v0.z; a0.w += v0.w;
        a1.x += v1.x; a1.y += v1.y; a1.z += v1.z; a1.w += v1.w;
    }
    if (j < s1) {
        float4 v = p4[csr_src[j] * LPN + fl];
        a0.x += v.x; a0.y += v.y; a0.z += v.z; a0.w += v.w;
    }
    float4 a = make_float4(a0.x + a1.x, a0.y + a1.y, a0.z + a1.z, a0.w + a1.w);
#pragma unroll
    for (int off = 32; off >= LPN; off >>= 1) {
        a.x += __shfl_down(a.x, off);
        a.y += __shfl_down(a.y, off);
        a.z += __shfl_down(a.z, off);
        a.w += __shfl_down(a.w, off);
    }
    if (lane < LPN) {
        float id = invdeg[g];
        float4 pr = reinterpret_cast<const float4*>(pre)[g * LPN + fl];
        float4 r;
        r.x = pr.x + a.x * id;
        r.y = pr.y + a.y * id;
        r.z = pr.z + a.z * id;
        r.w = pr.w + a.w * id;
        if (RELU) {
            r.x = fmaxf(r.x, 0.f); r.y = fmaxf(r.y, 0.f);
            r.z = fmaxf(r.z, 0.f); r.w = fmaxf(r.w, 0.f);
        }
        reinterpret_cast<float4*>(out)[g * LPN + fl] = r;
    }
}

extern "C" void kernel_launch(void* const* d_in, const int* in_sizes, int n_in,
                              void* d_out, int out_size, void* d_ws, size_t ws_size,
                              hipStream_t stream) {
    const float* x        = (const float*)d_in[0];
    const int*   edge_src = (const int*)d_in[1];
    const int*   edge_dst = (const int*)d_in[2];
    const float* Ws1 = (const float*)d_in[3];
    const float* Wn1 = (const float*)d_in[4];
    const float* b1  = (const float*)d_in[5];
    const float* Ws2 = (const float*)d_in[6];
    const float* Wn2 = (const float*)d_in[7];
    const float* b2  = (const float*)d_in[8];
    const float* Ws3 = (const float*)d_in[9];
    const float* Wn3 = (const float*)d_in[10];
    const float* b3  = (const float*)d_in[11];
    float* out = (float*)d_out;

    const int IN = 128, HID = 32;
    const int n_nodes = in_sizes[0] / IN;
    const int n_edges = in_sizes[1];
    const int nbuk = (n_nodes + (1 << BSH) - 1) >> BSH;   // 196
    const int ch   = (n_edges + NBLK - 1) / NBLK;         // 6250

    char* wsb = (char*)d_ws;
    size_t off = 0;
    auto alloc = [&](size_t bytes) { char* r = wsb + off; off = (off + bytes + 255) & ~(size_t)255; return r; };
    int*   startp = (int*)alloc(((size_t)n_nodes + 1) * sizeof(int));
    float* invdeg = (float*)alloc((size_t)n_nodes * sizeof(float));
    int*   csr    = (int*)alloc((size_t)n_edges * sizeof(int));
    int*   hist   = (int*)alloc((size_t)nbuk * NBLK * sizeof(int));
    int*   buktot = (int*)alloc(256 * sizeof(int));
    int*   bukoff = (int*)alloc(257 * sizeof(int));
    float* B0     = (float*)alloc((size_t)n_nodes * HID * sizeof(float));  // pre
    float* B1     = (float*)alloc((size_t)n_nodes * HID * sizeof(float));  // p
    float* B3     = (float*)alloc((size_t)n_nodes * HID * sizeof(float));  // h
    int2*  pairs  = (int2*)B0;   // CSR build fully precedes proj1 on the stream

    const int gP    = (n_nodes + 63) / 64;     // proj NT=64
    const int gGat  = (n_nodes + 3) / 4;

    // ---- CSR build: hist -> hierarchical scan -> partition -> per-bucket build ----
    hist_kernel   <<<NBLK, BLOCK, 0, stream>>>(edge_dst, hist, n_edges, nbuk, ch);
    scanBlk_kernel<<<nbuk, BLOCK, 0, stream>>>(hist, buktot);
    scanBuk_kernel<<<1, BLOCK, 0, stream>>>(buktot, bukoff, nbuk, startp, n_nodes, n_edges);
    part_kernel   <<<NBLK, BLOCK, 0, stream>>>(edge_src, edge_dst, hist, bukoff, pairs, n_edges, nbuk, ch);
    build_kernel  <<<nbuk, BLOCK, 0, stream>>>(pairs, bukoff, startp, invdeg, csr, n_nodes);

    // ---- layer 1: 128 -> 32, relu ----
    proj_reg<128, 32, 8, 2><<<gP, BLOCK, 0, stream>>>(x, Ws1, Wn1, b1, B0, B1, n_nodes);
    gather_kernel<32, true><<<gGat, BLOCK, 0, stream>>>(B1, csr, startp, B0, invdeg, B3, n_nodes);

    // ---- layer 2: 32 -> 32, relu ----
    proj_reg<32, 32, 8, 2><<<gP, BLOCK, 0, stream>>>(B3, Ws2, Wn2, b2, B0, B1, n_nodes);
    gather_kernel<32, true><<<gGat, BLOCK, 0, stream>>>(B1, csr, startp, B0, invdeg, B3, n_nodes);

    // ---- layer 3: 32 -> 16, no relu ----
    proj_reg<32, 16, 4, 2><<<gP, BLOCK, 0, stream>>>(B3, Ws3, Wn3, b3, B0, B1, n_nodes);
    gather_kernel<16, false><<<gGat, BLOCK, 0, stream>>>(B1, csr, startp, B0, invdeg, out, n_nodes);
}

// Round 12
// 216.918 us; speedup vs baseline: 1.2431x; 1.2431x over previous
//
#include <hip/hip_runtime.h>

// GraphSAGE 3-layer (mean agg), N=100000, E=1600000, 128->32->32->16.
// Round 12: round-10 proj body (W staged in LDS ONCE + x float4 global
// broadcast — round 11 proved global-W is VMEM-issue-bound: occ up, VALUBusy
// DOWN) with round-11's occupancy fix (NPT=2 -> NT=64 -> grid 1563 -> 4
// blocks/CU x 4 waves = 16 waves/CU, was 12). CSR build + gathers unchanged.

#define BLOCK 256
#define NBLK 256            // blocks for hist/part passes
#define BSH 9               // 512 nodes per bucket
#define CAP 12288           // max edges per bucket staged in LDS

// ---------------- phase 1: per-(bucket,block) histogram of dst ----------------
__global__ void hist_kernel(const int* __restrict__ dst, int* __restrict__ hist,
                            int n_edges, int nbuk, int ch) {
    __shared__ int cnt[256];
    int tid = threadIdx.x;
    for (int i = tid; i < nbuk; i += BLOCK) cnt[i] = 0;
    __syncthreads();
    int e0 = blockIdx.x * ch;
    int e1 = e0 + ch; if (e1 > n_edges) e1 = n_edges;
    for (int e = e0 + tid; e < e1; e += BLOCK)
        atomicAdd(&cnt[dst[e] >> BSH], 1);
    __syncthreads();
    for (int i = tid; i < nbuk; i += BLOCK)
        hist[i * NBLK + blockIdx.x] = cnt[i];
}

// ---------------- phase 2a: per-bucket exclusive scan of its 256 block-counts ----------------
__global__ void scanBlk_kernel(int* __restrict__ hist, int* __restrict__ buktot) {
    int b = blockIdx.x;
    int tid = threadIdx.x;
    int orig = hist[b * NBLK + tid];
    int v = orig;
    int lane = tid & 63, w = tid >> 6;
#pragma unroll
    for (int off = 1; off < 64; off <<= 1) {
        int u = __shfl_up(v, off);
        if (lane >= off) v += u;
    }
    __shared__ int wps[4];
    if (lane == 63) wps[w] = v;
    __syncthreads();
    int wadd = 0;
    for (int k = 0; k < w; ++k) wadd += wps[k];
    int excl = v - orig + wadd;
    hist[b * NBLK + tid] = excl;
    if (tid == 255) buktot[b] = excl + orig;
}

// ---------------- phase 2b: exclusive scan of bucket totals (1 block) ----------------
__global__ void scanBuk_kernel(const int* __restrict__ buktot, int* __restrict__ bukoff,
                               int nbuk, int* __restrict__ startp, int n_nodes, int n_edges) {
    int tid = threadIdx.x;
    int orig = (tid < nbuk) ? buktot[tid] : 0;
    int v = orig;
    int lane = tid & 63, w = tid >> 6;
#pragma unroll
    for (int off = 1; off < 64; off <<= 1) {
        int u = __shfl_up(v, off);
        if (lane >= off) v += u;
    }
    __shared__ int wps[4];
    if (lane == 63) wps[w] = v;
    __syncthreads();
    int wadd = 0;
    for (int k = 0; k < w; ++k) wadd += wps[k];
    int excl = v - orig + wadd;
    if (tid < nbuk) bukoff[tid] = excl;
    if (tid == 0) { bukoff[nbuk] = n_edges; startp[n_nodes] = n_edges; }
}

// ---------------- phase 3: partition (src,dst) pairs bucket-contiguously ----------------
__global__ void part_kernel(const int* __restrict__ src, const int* __restrict__ dst,
                            const int* __restrict__ hist, const int* __restrict__ bukoff,
                            int2* __restrict__ pairs, int n_edges, int nbuk, int ch) {
    __shared__ int base[256];
    __shared__ int cnt[256];
    int tid = threadIdx.x;
    for (int i = tid; i < nbuk; i += BLOCK) {
        base[i] = hist[i * NBLK + blockIdx.x] + bukoff[i];
        cnt[i] = 0;
    }
    __syncthreads();
    int e0 = blockIdx.x * ch;
    int e1 = e0 + ch; if (e1 > n_edges) e1 = n_edges;
    for (int e = e0 + tid; e < e1; e += BLOCK) {
        int d = dst[e];
        int b = d >> BSH;
        int r = atomicAdd(&cnt[b], 1);
        pairs[base[b] + r] = make_int2(src[e], d);
    }
}

// ---------------- phase 4: per-bucket CSR build in LDS ----------------
__global__ void build_kernel(const int2* __restrict__ pairs, const int* __restrict__ bukoff,
                             int* __restrict__ start, float* __restrict__ invdeg,
                             int* __restrict__ csr_src, int n_nodes) {
    __shared__ int deg[512];
    __shared__ int lst[512];
    __shared__ int cur[512];
    __shared__ int wps[4];
    __shared__ int scsr[CAP];

    int b = blockIdx.x;
    int tid = threadIdx.x;
    int e0 = bukoff[b];
    int e1 = bukoff[b + 1];
    int lo = b << BSH;
    int hi = lo + (1 << BSH); if (hi > n_nodes) hi = n_nodes;
    int nn = hi - lo;
    int ne = e1 - e0;

    for (int i = tid; i < 512; i += BLOCK) deg[i] = 0;
    __syncthreads();
    for (int i = e0 + tid; i < e1; i += BLOCK)
        atomicAdd(&deg[pairs[i].y - lo], 1);
    __syncthreads();

    int d0 = deg[2 * tid], d1 = deg[2 * tid + 1];
    int s = d0 + d1;
    int lane = tid & 63, w = tid >> 6;
    int v = s;
#pragma unroll
    for (int off = 1; off < 64; off <<= 1) {
        int u = __shfl_up(v, off);
        if (lane >= off) v += u;
    }
    if (lane == 63) wps[w] = v;
    __syncthreads();
    int wb = 0;
    for (int k = 0; k < w; ++k) wb += wps[k];
    int excl = wb + v - s;
    lst[2 * tid] = excl;
    lst[2 * tid + 1] = excl + d0;
    cur[2 * tid] = 0;
    cur[2 * tid + 1] = 0;
    __syncthreads();

    for (int i = tid; i < nn; i += BLOCK) {
        start[lo + i] = e0 + lst[i];
        int d = deg[i];
        invdeg[lo + i] = 1.0f / (float)(d < 1 ? 1 : d);
    }

    if (ne <= CAP) {
        for (int i = e0 + tid; i < e1; i += BLOCK) {
            int2 pr = pairs[i];
            int dl = pr.y - lo;
            int sl = lst[dl] + atomicAdd(&cur[dl], 1);
            scsr[sl] = pr.x;
        }
        __syncthreads();
        for (int i = tid; i < ne; i += BLOCK) csr_src[e0 + i] = scsr[i];
    } else {
        for (int i = e0 + tid; i < e1; i += BLOCK) {
            int2 pr = pairs[i];
            int dl = pr.y - lo;
            int sl = lst[dl] + atomicAdd(&cur[dl], 1);
            csr_src[e0 + sl] = pr.x;
        }
    }
}

// ---------------- projection: pre = h@Ws + b ; p = h@Wn ----------------
// W + bias staged in LDS once (one barrier). x loaded directly from global as
// float4 (8 lanes of an output-group share the address -> broadcast fetch).
// NPT=2 -> NT=64 -> grid ~1563 for occupancy (LDS 33KB -> 4 blocks/CU).
template<int DIN, int DOUT, int OPT, int NPT>
__global__ __launch_bounds__(256, 4)
void proj_reg(const float* __restrict__ h,
              const float* __restrict__ Ws,
              const float* __restrict__ Wn,
              const float* __restrict__ bias,
              float* __restrict__ pre,
              float* __restrict__ p,
              int n_nodes) {
    constexpr int OD  = 2 * DOUT;
    constexpr int OG  = OD / OPT;       // output groups
    constexpr int NG  = 256 / OG;       // node groups
    constexpr int NT  = NPT * NG;       // node tile
    constexpr int NV  = OPT / 4;        // float4s of output per thread

    __shared__ float sW[DIN][OD];
    __shared__ float sb[DOUT];

    const int tid = threadIdx.x;
    for (int i = tid; i < DIN * OD; i += 256) {
        int k = i / OD, o = i % OD;
        sW[k][o] = (o < DOUT) ? Ws[k * DOUT + o] : Wn[k * DOUT + (o - DOUT)];
    }
    if (tid < DOUT) sb[tid] = bias[tid];
    __syncthreads();

    const int to = tid % OG;
    const int tn = tid / OG;
    const int o0 = to * OPT;
    const int node0 = blockIdx.x * NT + tn * NPT;

    const float4* __restrict__ xp[NPT];
#pragma unroll
    for (int n = 0; n < NPT; ++n) {
        int node = node0 + n;
        int safe = (node < n_nodes) ? node : (n_nodes - 1);
        xp[n] = reinterpret_cast<const float4*>(h + (size_t)safe * DIN);
    }

    float acc[NPT][OPT];
#pragma unroll
    for (int n = 0; n < NPT; ++n)
#pragma unroll
        for (int o = 0; o < OPT; ++o) acc[n][o] = 0.f;

#pragma unroll 2
    for (int k4 = 0; k4 < DIN / 4; ++k4) {
        float4 xv[NPT];
#pragma unroll
        for (int n = 0; n < NPT; ++n) xv[n] = xp[n][k4];
#pragma unroll
        for (int kk = 0; kk < 4; ++kk) {
            int k = 4 * k4 + kk;
            float4 w[NV];
#pragma unroll
            for (int v = 0; v < NV; ++v)
                w[v] = *reinterpret_cast<const float4*>(&sW[k][o0 + 4 * v]);
#pragma unroll
            for (int n = 0; n < NPT; ++n) {
                float xk = reinterpret_cast<const float*>(&xv[n])[kk];
#pragma unroll
                for (int v = 0; v < NV; ++v) {
                    acc[n][4 * v + 0] = fmaf(xk, w[v].x, acc[n][4 * v + 0]);
                    acc[n][4 * v + 1] = fmaf(xk, w[v].y, acc[n][4 * v + 1]);
                    acc[n][4 * v + 2] = fmaf(xk, w[v].z, acc[n][4 * v + 2]);
                    acc[n][4 * v + 3] = fmaf(xk, w[v].w, acc[n][4 * v + 3]);
                }
            }
        }
    }

    const bool self_half = (o0 < DOUT);
    const int oo = self_half ? o0 : (o0 - DOUT);
    float* __restrict__ dstbuf = self_half ? pre : p;
#pragma unroll
    for (int n = 0; n < NPT; ++n) {
        int node = node0 + n;
        if (node >= n_nodes) continue;
#pragma unroll
        for (int v = 0; v < NV; ++v) {
            float4 r;
            r.x = acc[n][4 * v + 0];
            r.y = acc[n][4 * v + 1];
            r.z = acc[n][4 * v + 2];
            r.w = acc[n][4 * v + 3];
            if (self_half) {
                r.x += sb[oo + 4 * v + 0];
                r.y += sb[oo + 4 * v + 1];
                r.z += sb[oo + 4 * v + 2];
                r.w += sb[oo + 4 * v + 3];
            }
            *reinterpret_cast<float4*>(dstbuf + (size_t)node * DOUT + oo + 4 * v) = r;
        }
    }
}

// ---------------- float4 sub-group gather + finalize ----------------
template<int D, bool RELU>
__global__ void gather_kernel(const float* __restrict__ p,
                              const int* __restrict__ csr_src,
                              const int* __restrict__ start,
                              const float* __restrict__ pre,
                              const float* __restrict__ invdeg,
                              float* __restrict__ out,
                              int n_nodes) {
    constexpr int LPN = D / 4;
    constexpr int NPG = 64 / LPN;
    int wave = threadIdx.x >> 6;
    int lane = threadIdx.x & 63;
    int g = blockIdx.x * (blockDim.x >> 6) + wave;
    if (g >= n_nodes) return;
    int sub = lane / LPN;
    int fl  = lane % LPN;
    int s0 = start[g];
    int s1 = start[g + 1];
    const float4* __restrict__ p4 = reinterpret_cast<const float4*>(p);
    float4 a0 = make_float4(0.f, 0.f, 0.f, 0.f);
    float4 a1 = make_float4(0.f, 0.f, 0.f, 0.f);
    int j = s0 + sub;
    for (; j + NPG < s1; j += 2 * NPG) {
        int c0 = csr_src[j];
        int c1 = csr_src[j + NPG];
        float4 v0 = p4[c0 * LPN + fl];
        float4 v1 = p4[c1 * LPN + fl];
        a0.x += v0.x; a0.y += v0.y; a0.z += v0.z; a0.w += v0.w;
        a1.x += v1.x; a1.y += v1.y; a1.z += v1.z; a1.w += v1.w;
    }
    if (j < s1) {
        float4 v = p4[csr_src[j] * LPN + fl];
        a0.x += v.x; a0.y += v.y; a0.z += v.z; a0.w += v.w;
    }
    float4 a = make_float4(a0.x + a1.x, a0.y + a1.y, a0.z + a1.z, a0.w + a1.w);
#pragma unroll
    for (int off = 32; off >= LPN; off >>= 1) {
        a.x += __shfl_down(a.x, off);
        a.y += __shfl_down(a.y, off);
        a.z += __shfl_down(a.z, off);
        a.w += __shfl_down(a.w, off);
    }
    if (lane < LPN) {
        float id = invdeg[g];
        float4 pr = reinterpret_cast<const float4*>(pre)[g * LPN + fl];
        float4 r;
        r.x = pr.x + a.x * id;
        r.y = pr.y + a.y * id;
        r.z = pr.z + a.z * id;
        r.w = pr.w + a.w * id;
        if (RELU) {
            r.x = fmaxf(r.x, 0.f); r.y = fmaxf(r.y, 0.f);
            r.z = fmaxf(r.z, 0.f); r.w = fmaxf(r.w, 0.f);
        }
        reinterpret_cast<float4*>(out)[g * LPN + fl] = r;
    }
}

extern "C" void kernel_launch(void* const* d_in, const int* in_sizes, int n_in,
                              void* d_out, int out_size, void* d_ws, size_t ws_size,
                              hipStream_t stream) {
    const float* x        = (const float*)d_in[0];
    const int*   edge_src = (const int*)d_in[1];
    const int*   edge_dst = (const int*)d_in[2];
    const float* Ws1 = (const float*)d_in[3];
    const float* Wn1 = (const float*)d_in[4];
    const float* b1  = (const float*)d_in[5];
    const float* Ws2 = (const float*)d_in[6];
    const float* Wn2 = (const float*)d_in[7];
    const float* b2  = (const float*)d_in[8];
    const float* Ws3 = (const float*)d_in[9];
    const float* Wn3 = (const float*)d_in[10];
    const float* b3  = (const float*)d_in[11];
    float* out = (float*)d_out;

    const int IN = 128, HID = 32;
    const int n_nodes = in_sizes[0] / IN;
    const int n_edges = in_sizes[1];
    const int nbuk = (n_nodes + (1 << BSH) - 1) >> BSH;   // 196
    const int ch   = (n_edges + NBLK - 1) / NBLK;         // 6250

    char* wsb = (char*)d_ws;
    size_t off = 0;
    auto alloc = [&](size_t bytes) { char* r = wsb + off; off = (off + bytes + 255) & ~(size_t)255; return r; };
    int*   startp = (int*)alloc(((size_t)n_nodes + 1) * sizeof(int));
    float* invdeg = (float*)alloc((size_t)n_nodes * sizeof(float));
    int*   csr    = (int*)alloc((size_t)n_edges * sizeof(int));
    int*   hist   = (int*)alloc((size_t)nbuk * NBLK * sizeof(int));
    int*   buktot = (int*)alloc(256 * sizeof(int));
    int*   bukoff = (int*)alloc(257 * sizeof(int));
    float* B0     = (float*)alloc((size_t)n_nodes * HID * sizeof(float));  // pre
    float* B1     = (float*)alloc((size_t)n_nodes * HID * sizeof(float));  // p
    float* B3     = (float*)alloc((size_t)n_nodes * HID * sizeof(float));  // h
    int2*  pairs  = (int2*)B0;   // CSR build fully precedes proj1 on the stream

    const int gP    = (n_nodes + 63) / 64;     // proj NT=64
    const int gGat  = (n_nodes + 3) / 4;

    // ---- CSR build: hist -> hierarchical scan -> partition -> per-bucket build ----
    hist_kernel   <<<NBLK, BLOCK, 0, stream>>>(edge_dst, hist, n_edges, nbuk, ch);
    scanBlk_kernel<<<nbuk, BLOCK, 0, stream>>>(hist, buktot);
    scanBuk_kernel<<<1, BLOCK, 0, stream>>>(buktot, bukoff, nbuk, startp, n_nodes, n_edges);
    part_kernel   <<<NBLK, BLOCK, 0, stream>>>(edge_src, edge_dst, hist, bukoff, pairs, n_edges, nbuk, ch);
    build_kernel  <<<nbuk, BLOCK, 0, stream>>>(pairs, bukoff, startp, invdeg, csr, n_nodes);

    // ---- layer 1: 128 -> 32, relu ----
    proj_reg<128, 32, 8, 2><<<gP, BLOCK, 0, stream>>>(x, Ws1, Wn1, b1, B0, B1, n_nodes);
    gather_kernel<32, true><<<gGat, BLOCK, 0, stream>>>(B1, csr, startp, B0, invdeg, B3, n_nodes);

    // ---- layer 2: 32 -> 32, relu ----
    proj_reg<32, 32, 8, 2><<<gP, BLOCK, 0, stream>>>(B3, Ws2, Wn2, b2, B0, B1, n_nodes);
    gather_kernel<32, true><<<gGat, BLOCK, 0, stream>>>(B1, csr, startp, B0, invdeg, B3, n_nodes);

    // ---- layer 3: 32 -> 16, no relu ----
    proj_reg<32, 16, 4, 2><<<gP, BLOCK, 0, stream>>>(B3, Ws3, Wn3, b3, B0, B1, n_nodes);
    gather_kernel<16, false><<<gGat, BLOCK, 0, stream>>>(B1, csr, startp, B0, invdeg, out, n_nodes);
}